// Round 12
// baseline (402.104 us; speedup 1.0000x reference)
//
#include <hip/hip_runtime.h>
#include <hip/hip_bf16.h>
#include <stdint.h>

#define XS 128
#define YS 128
#define ZS 8
#define NQ (XS*YS*ZS)        // 131072 queries
#define CDIM 128
#define NH 8
#define HD 16
#define DH 192
#define DW 640
#define NPIX (DH*DW)
#define NVPIX 10080          // 7680 + 1920 + 480

typedef float f32x4 __attribute__((ext_vector_type(4)));
typedef short s16x8 __attribute__((ext_vector_type(8)));
typedef unsigned int u32x4 __attribute__((ext_vector_type(4)));

__device__ __forceinline__ float b2f(unsigned short u){
    union { unsigned int i; float f; } v; v.i = ((unsigned int)u) << 16; return v.f;
}
__device__ __forceinline__ unsigned short f2b(float f){
    __hip_bfloat16 h = __float2bfloat16(f);
    return *reinterpret_cast<unsigned short*>(&h);
}
__device__ __forceinline__ float blo(unsigned int u){
    union { unsigned int i; float f; } v; v.i = u << 16; return v.f;
}
__device__ __forceinline__ float bhi(unsigned int u){
    union { unsigned int i; float f; } v; v.i = u & 0xffff0000u; return v.f;
}

// ====== fused prep: Wbf build | value GEMM | mask (fp64 inverse in-block) ======
// Roles by blockIdx.x: [0,nW) weights ; [nW,nW+nVal) value ; rest mask.
__global__ __launch_bounds__(256)
void prep_kernel(int nW, int nVal,
                 const float* __restrict__ Woff,
                 const float* __restrict__ Wattw,
                 const float* __restrict__ Wout,
                 unsigned short* __restrict__ Wbf,
                 const float* __restrict__ f0,
                 const float* __restrict__ f1,
                 const float* __restrict__ f2,
                 const float* __restrict__ Wv,
                 const float* __restrict__ bv,
                 unsigned short* __restrict__ value,  // [NH][NVPIX][HD]
                 const float* __restrict__ depth,
                 const float* __restrict__ K,
                 const float* __restrict__ E,
                 const float* __restrict__ vorigin,
                 unsigned char* __restrict__ mask){
    __shared__ __align__(16) unsigned char smem[16384];
    const int t = threadIdx.x;

    if ((int)blockIdx.x < nW){
        // ---------- Wbf: [0,24576) Woff | Wattw | zero pad | Wout ----------
        int idx = blockIdx.x*256 + t;
        if (idx < 24576)      Wbf[idx] = f2b(Woff[idx]);
        else if (idx < 36864) Wbf[idx] = f2b(Wattw[idx-24576]);
        else if (idx < 40960) Wbf[idx] = 0;
        else if (idx < 57344) Wbf[idx] = f2b(Wout[idx-40960]);
    } else if ((int)blockIdx.x < nW + nVal){
        // ---------- value: 8 pixels per block (two 128-thread halves) ----------
        const int half = t >> 7, tt = t & 127;
        const int p0 = (blockIdx.x - nW)*8 + half*4;
        float (*fl)[4] = (float(*)[4])(smem + half*2048);
        const float* src; int hw, lp;
        if (p0 < 7680)      { src=f0; hw=7680; lp=p0; }
        else if (p0 < 9600) { src=f1; hw=1920; lp=p0-7680; }
        else                { src=f2; hw=480;  lp=p0-9600; }
        float4 v = *(const float4*)(src + tt*hw + lp);
        fl[tt][0]=v.x; fl[tt][1]=v.y; fl[tt][2]=v.z; fl[tt][3]=v.w;
        __syncthreads();
        float bb = bv[tt];
        float acc[4] = {bb,bb,bb,bb};
        const float4* wrow = (const float4*)(Wv + tt*CDIM);
        #pragma unroll 8
        for (int kc=0; kc<32; ++kc){
            float4 w = wrow[kc];
            #pragma unroll
            for (int u=0;u<4;u++){
                float wu = (u==0)?w.x:(u==1)?w.y:(u==2)?w.z:w.w;
                float4 fv = *(const float4*)fl[kc*4+u];
                acc[0] += fv.x*wu; acc[1] += fv.y*wu; acc[2] += fv.z*wu; acc[3] += fv.w*wu;
            }
        }
        const int hh = tt >> 4, cc = tt & 15;
        #pragma unroll
        for (int i=0;i<4;i++)
            value[((size_t)hh*NVPIX + (size_t)(p0+i))*HD + cc] = f2b(acc[i]);
    } else {
        // ---------- mask: fp64 K/E inverse computed per block, LDS broadcast ----------
        double* invs = (double*)smem;    // [21]: invK 9 | invE rows 0..2 (12)
        if (t == 0){
            double k[3][3], e[4][4];
            for (int i=0;i<9;i++)  k[i/3][i%3] = (double)K[i];
            for (int i=0;i<16;i++) e[i/4][i%4] = (double)E[i];
            double det = k[0][0]*(k[1][1]*k[2][2]-k[1][2]*k[2][1])
                       - k[0][1]*(k[1][0]*k[2][2]-k[1][2]*k[2][0])
                       + k[0][2]*(k[1][0]*k[2][1]-k[1][1]*k[2][0]);
            double id = 1.0/det;
            invs[0]=(k[1][1]*k[2][2]-k[1][2]*k[2][1])*id;
            invs[1]=(k[0][2]*k[2][1]-k[0][1]*k[2][2])*id;
            invs[2]=(k[0][1]*k[1][2]-k[0][2]*k[1][1])*id;
            invs[3]=(k[1][2]*k[2][0]-k[1][0]*k[2][2])*id;
            invs[4]=(k[0][0]*k[2][2]-k[0][2]*k[2][0])*id;
            invs[5]=(k[0][2]*k[1][0]-k[0][0]*k[1][2])*id;
            invs[6]=(k[1][0]*k[2][1]-k[1][1]*k[2][0])*id;
            invs[7]=(k[0][1]*k[2][0]-k[0][0]*k[2][1])*id;
            invs[8]=(k[0][0]*k[1][1]-k[0][1]*k[1][0])*id;
            double a[4][8];
            for (int i=0;i<4;i++){ for(int j=0;j<4;j++){ a[i][j]=e[i][j]; a[i][4+j]=(i==j)?1.0:0.0; } }
            for (int c=0;c<4;c++){
                int piv=c; double best=fabs(a[c][c]);
                for (int r=c+1;r<4;r++){ double v=fabs(a[r][c]); if (v>best){best=v;piv=r;} }
                if (piv!=c){ for (int j=0;j<8;j++){ double tmp=a[c][j]; a[c][j]=a[piv][j]; a[piv][j]=tmp; } }
                double pv = 1.0/a[c][c];
                for (int j=0;j<8;j++) a[c][j]*=pv;
                for (int r=0;r<4;r++){
                    if (r==c) continue;
                    double f=a[r][c];
                    for(int j=0;j<8;j++) a[r][j]-=f*a[c][j];
                }
            }
            for (int i=0;i<12;i++) invs[9+i] = a[i/4][4 + (i%4)];
        }
        __syncthreads();
        int tid = ((int)blockIdx.x - nW - nVal)*256 + t;
        if (tid >= NPIX) return;
        int gx = tid % DW, gy = tid / DW;
        double d  = (double)depth[tid];
        double X0 = (double)gx * d, X1 = (double)gy * d, X2 = d;
        double c0 = invs[0]*X0 + invs[1]*X1 + invs[2]*X2;
        double c1 = invs[3]*X0 + invs[4]*X1 + invs[5]*X2;
        double c2 = invs[6]*X0 + invs[7]*X1 + invs[8]*X2;
        const double* iE = invs + 9;
        double w0 = iE[0]*c0 + iE[1]*c1 + iE[2]*c2  + iE[3];
        double w1 = iE[4]*c0 + iE[5]*c1 + iE[6]*c2  + iE[7];
        double w2 = iE[8]*c0 + iE[9]*c1 + iE[10]*c2 + iE[11];
        double v0 = (w0-(double)vorigin[0])/0.4 - 0.5;
        double v1 = (w1-(double)vorigin[1])/0.4 - 0.5;
        double v2 = ((w2-(double)vorigin[2])/0.4 - 0.5) / 2.0;
        int xi = (int)v0, yi = (int)v1, zi = (int)v2;
        if (xi>=0 && xi<XS && yi>=0 && yi<YS && zi>=0 && zi<ZS)
            mask[(xi*YS + yi)*ZS + zi] = 1;
    }
}

// ======== attn_fused32: offaw MFMA + softmax + 4x{desc, qv-prefetch, sampling, Wout, LN} ========
__global__ __launch_bounds__(256, 2)
void attn_fused(const float* __restrict__ q_in,
                const float* __restrict__ refpix,
                const unsigned short* __restrict__ Wbf,    // [320][128] bf16 (padded)
                const float* __restrict__ boff,
                const float* __restrict__ battw,
                const unsigned short* __restrict__ value,  // [NH][NVPIX][HD]
                const unsigned short* __restrict__ WoutBf, // [128][128] bf16
                const float* __restrict__ bout,
                const float* __restrict__ lng,
                const float* __restrict__ lnb,
                const unsigned char* __restrict__ mask,
                float* __restrict__ dout){
    const int nq0 = blockIdx.x * 32;
    const int t = threadIdx.x;
    __shared__ __align__(16) unsigned char smem[36384];
    unsigned short* Ob    = (unsigned short*)smem;
    unsigned char*  qbfB  = smem + 18432;
    unsigned char*  descB = smem + 18432;
    float*          out2  = (float*)(smem + 18432);
    unsigned char*  obfB  = smem + 30720;
    float*          bias  = (float*)(smem + 34816);
    float*          rp_s  = (float*)(smem + 35968);
    unsigned char*  mask_s= smem + 36224;
    float*          wredp = (float*)(smem + 36256);

    // ---- stage: q -> swizzled bf16, bias, rp, mask, zero obf pad rows ----
    #pragma unroll
    for (int i=0;i<4;i++){
        int idx = t + i*256;              // 1024 float4s = 32 rows x 32
        int row = idx >> 5, c4 = idx & 31;
        float4 qv = ((const float4*)(q_in + (size_t)(nq0+row)*CDIM))[c4];
        unsigned int pk0 = (unsigned int)f2b(qv.x) | ((unsigned int)f2b(qv.y)<<16);
        unsigned int pk1 = (unsigned int)f2b(qv.z) | ((unsigned int)f2b(qv.w)<<16);
        unsigned int bo = ((unsigned int)(row*256 + c4*8)) ^ (unsigned int)((row&7)<<4);
        *(unsigned int*)(qbfB + bo)     = pk0;
        *(unsigned int*)(qbfB + bo + 4) = pk1;
    }
    for (int i=t;i<288;i+=256) bias[i] = (i<192)? boff[i] : battw[i-192];
    ((unsigned int*)obfB)[512 + t] = 0;   // zero obf rows 8..15
    ((unsigned int*)obfB)[768 + t] = 0;
    if (t < 64) rp_s[t] = refpix[nq0*2 + t];
    if (t < 32) mask_s[t] = mask[nq0 + t];
    __syncthreads();

    // ---- offaw MFMA: 5 feature tiles x 2 query tiles x 4 K-steps per wave ----
    {
        const int w = t >> 6, lane = t & 63, lr = lane & 15, lg = lane >> 4;
        const int nt0 = w*5;
        f32x4 acc[5][2];
        #pragma unroll
        for (int j=0;j<5;j++){ acc[j][0]=(f32x4){0,0,0,0}; acc[j][1]=(f32x4){0,0,0,0}; }
        #pragma unroll
        for (int ks=0; ks<4; ++ks){
            s16x8 bf[2];
            #pragma unroll
            for (int qt=0;qt<2;qt++){
                int qrow = qt*16 + lr;
                unsigned int bo = ((unsigned int)(qrow*256 + ks*64 + lg*16)) ^ (unsigned int)((qrow&7)<<4);
                bf[qt] = *(const s16x8*)(qbfB + bo);
            }
            const unsigned short* wp = Wbf + (size_t)(nt0*16 + lr)*CDIM + ks*32 + lg*8;
            #pragma unroll
            for (int j=0;j<5;++j){
                s16x8 af = *(const s16x8*)(wp + j*16*CDIM);
                acc[j][0] = __builtin_amdgcn_mfma_f32_16x16x32_bf16(af, bf[0], acc[j][0], 0, 0, 0);
                acc[j][1] = __builtin_amdgcn_mfma_f32_16x16x32_bf16(af, bf[1], acc[j][1], 0, 0, 0);
            }
        }
        #pragma unroll
        for (int j=0;j<5;++j){
            int nt = nt0 + j;
            if (nt < 18){
                #pragma unroll
                for (int qt=0;qt<2;qt++){
                    int q = qt*16 + lr;
                    int base = (q>>3)*2304 + (q&7);
                    #pragma unroll
                    for (int r=0;r<4;++r){
                        int f = nt*16 + lg*4 + r;
                        Ob[base + f*8] = f2b(acc[j][qt][r] + bias[f]);
                    }
                }
            }
        }
    }
    __syncthreads();

    // ---- softmax: 32q x 8h = 256 tasks, one per thread ----
    {
        int q = t >> 3, h = t & 7;
        unsigned short* p = Ob + (q>>3)*2304 + (192 + h*12)*8 + (q&7);
        float e[12]; float m = -1e30f;
        #pragma unroll
        for (int i=0;i<12;i++){ e[i] = b2f(p[i*8]); m = fmaxf(m, e[i]); }
        float s = 0.f;
        #pragma unroll
        for (int i=0;i<12;i++){ e[i] = __expf(e[i]-m); s += e[i]; }
        float is = 1.f/s;
        #pragma unroll
        for (int i=0;i<12;i++) p[i*8] = f2b(e[i]*is);
    }
    __syncthreads();

    // ---- 4 sub-rounds of 8 queries ----
    for (int sr = 0; sr < 4; ++sr){
        const unsigned short* raw = Ob + sr*2304;
        const int nsr = nq0 + sr*8;

        // desc: 768 sample descriptors
        for (int idx = t; idx < 768; idx += 256){
            int q = idx & 7, hp = idx >> 3;
            int lp = hp % 12;
            float fw, fh; int Wl, Hl, st;
            if (lp < 4)      { fw=160.f; fh=48.f; Wl=160; Hl=48; st=0; }
            else if (lp < 8) { fw=80.f;  fh=24.f; Wl=80;  Hl=24; st=7680; }
            else             { fw=40.f;  fh=12.f; Wl=40;  Hl=12; st=9600; }
            float offx = b2f(raw[(hp*2)*8 + q]);
            float offy = b2f(raw[(hp*2+1)*8 + q]);
            float aw   = b2f(raw[(192+hp)*8 + q]);
            float x = rp_s[(sr*8+q)*2+0]*fw - 0.5f + offx;
            float y = rp_s[(sr*8+q)*2+1]*fh - 0.5f + offy;
            float x0f = floorf(x), y0f = floorf(y);
            float lx = x-x0f, ly = y-y0f;
            int x0 = (int)x0f, y0 = (int)y0f;
            bool x0ok = (x0>=0)&&(x0<Wl), x1ok=(x0+1>=0)&&(x0+1<Wl);
            bool y0ok = (y0>=0)&&(y0<Hl), y1ok=(y0+1>=0)&&(y0+1<Hl);
            float w00 = (x0ok&&y0ok)? (1.f-lx)*(1.f-ly)*aw : 0.f;
            float w01 = (x1ok&&y0ok)? lx*(1.f-ly)*aw       : 0.f;
            float w10 = (x0ok&&y1ok)? (1.f-lx)*ly*aw       : 0.f;
            float w11 = (x1ok&&y1ok)? lx*ly*aw             : 0.f;
            int yc0 = min(max(y0,0),Hl-1), yc1 = min(max(y0+1,0),Hl-1);
            int xc0 = min(max(x0,0),Wl-1), xc1 = min(max(x0+1,0),Wl-1);
            unsigned int rb0 = (unsigned int)(st + yc0*Wl), rb1 = (unsigned int)(st + yc1*Wl);
            uint4 d;
            d.x = (rb0+(unsigned int)xc0) | ((rb0+(unsigned int)xc1)<<16);
            d.y = (rb1+(unsigned int)xc0) | ((rb1+(unsigned int)xc1)<<16);
            d.z = (unsigned int)f2b(w00) | ((unsigned int)f2b(w01)<<16);
            d.w = (unsigned int)f2b(w10) | ((unsigned int)f2b(w11)<<16);
            *(uint4*)(descB + (((unsigned int)(idx ^ ((idx>>5)&7)))<<4)) = d;
        }
        __syncthreads();

        // qv prefetch: issue residual q loads now (hidden under sampling)
        float qv[4];
        {
            const int r = t & 127, qb = t >> 7;
            #pragma unroll
            for (int qi4=0;qi4<4;qi4++)
                qv[qi4] = q_in[(size_t)(nsr + qb*4 + qi4)*CDIM + r];
        }

        // sampling: 8 channels x 1 query x 2 corners per thread, dwordx4 gathers
        {
            const int cs  = t & 1;          // corner pair: 0->(00,01), 1->(10,11)
            const int cp2 = (t >> 1) & 1;   // channel group cp2*8 .. +7
            const int hs  = (t >> 2) & 7;
            const int qq  = t >> 5;         // 0..7
            const unsigned int vbase = (unsigned int)hs*(NVPIX*HD*2) + (unsigned int)cp2*16;
            const char* vb = (const char*)value;
            float a8[8] = {0.f,0.f,0.f,0.f,0.f,0.f,0.f,0.f};
            #pragma unroll
            for (int lp=0; lp<12; ++lp){
                int idx = (hs*12+lp)*8 + qq;
                uint4 d = *(const uint4*)(descB + (((unsigned int)(idx ^ ((idx>>5)&7)))<<4));
                unsigned int pidx = cs ? d.y : d.x;
                unsigned int wpk  = cs ? d.w : d.z;
                unsigned int oa = vbase + ((pidx & 0xffffu)<<5);
                unsigned int ob = vbase + ((pidx >> 16)<<5);
                u32x4 ua = *(const u32x4*)(vb + oa);
                u32x4 ub = *(const u32x4*)(vb + ob);
                float wa = blo(wpk), wb = bhi(wpk);
                #pragma unroll
                for (int j=0;j<4;j++){
                    a8[2*j]   += blo(ua[j])*wa + blo(ub[j])*wb;
                    a8[2*j+1] += bhi(ua[j])*wa + bhi(ub[j])*wb;
                }
            }
            // combine corner-pair partners (lane t^1, same wave)
            #pragma unroll
            for (int j=0;j<8;j++) a8[j] += __shfl_xor(a8[j], 1, 64);
            if (cs == 0){
                u32x4 pk;
                pk[0] = (unsigned int)f2b(a8[0]) | ((unsigned int)f2b(a8[1])<<16);
                pk[1] = (unsigned int)f2b(a8[2]) | ((unsigned int)f2b(a8[3])<<16);
                pk[2] = (unsigned int)f2b(a8[4]) | ((unsigned int)f2b(a8[5])<<16);
                pk[3] = (unsigned int)f2b(a8[6]) | ((unsigned int)f2b(a8[7])<<16);
                unsigned int bo = ((unsigned int)(qq*256 + hs*32 + cp2*16)) ^ (unsigned int)((qq&7)<<4);
                *(u32x4*)(obfB + bo) = pk;
            }
        }
        __syncthreads();

        // Wout projection via MFMA, bout folded
        {
            const int w = t >> 6, lane = t & 63, lr = lane & 15, lg = lane >> 4;
            f32x4 a0 = (f32x4){0.f,0.f,0.f,0.f};
            f32x4 a1 = (f32x4){0.f,0.f,0.f,0.f};
            #pragma unroll
            for (int ks=0; ks<4; ++ks){
                unsigned int bo = (unsigned int)(lr*256 + ks*64 + lg*16) ^ (unsigned int)((lr&7)<<4);
                s16x8 bfrag = *(const s16x8*)(obfB + bo);
                const unsigned short* wp = WoutBf + (size_t)(w*32 + lr)*CDIM + ks*32 + lg*8;
                s16x8 af0 = *(const s16x8*)(wp);
                s16x8 af1 = *(const s16x8*)(wp + 16*CDIM);
                a0 = __builtin_amdgcn_mfma_f32_16x16x32_bf16(af0, bfrag, a0, 0, 0, 0);
                a1 = __builtin_amdgcn_mfma_f32_16x16x32_bf16(af1, bfrag, a1, 0, 0, 0);
            }
            if (lr < 8){
                int f0 = w*32 + lg*4;
                float4 b0 = *(const float4*)(bout + f0);
                float4 b1 = *(const float4*)(bout + f0 + 16);
                float4 v0, v1;
                v0.x = a0[0]+b0.x; v0.y = a0[1]+b0.y; v0.z = a0[2]+b0.z; v0.w = a0[3]+b0.w;
                v1.x = a1[0]+b1.x; v1.y = a1[1]+b1.y; v1.z = a1[2]+b1.z; v1.w = a1[3]+b1.w;
                *(float4*)(out2 + lr*CDIM + f0)      = v0;
                *(float4*)(out2 + lr*CDIM + f0 + 16) = v1;
            }
        }
        __syncthreads();

        // residual (prefetched qv) + single-pass LN + mask + store
        {
            const int r = t & 127;
            const int qb = t >> 7;
            const int wv = t >> 6;
            float hv[4], s1[4], s2[4];
            #pragma unroll
            for (int qi4=0;qi4<4;qi4++){
                hv[qi4] = qv[qi4] + out2[(qb*4+qi4)*CDIM + r];
                s1[qi4] = hv[qi4];
                s2[qi4] = hv[qi4]*hv[qi4];
            }
            #pragma unroll
            for (int off=32; off>0; off>>=1){
                #pragma unroll
                for (int qi4=0;qi4<4;qi4++){
                    s1[qi4] += __shfl_xor(s1[qi4], off, 64);
                    s2[qi4] += __shfl_xor(s2[qi4], off, 64);
                }
            }
            if ((t&63)==0){
                #pragma unroll
                for (int qi4=0;qi4<4;qi4++){
                    wredp[0*16 + wv*4 + qi4] = s1[qi4];
                    wredp[1*16 + wv*4 + qi4] = s2[qi4];
                }
            }
            __syncthreads();

            float res[4];
            const float g = lng[r], b = lnb[r];
            #pragma unroll
            for (int qi4=0;qi4<4;qi4++){
                float mu  = (wredp[0*16 + (qb*2)*4 + qi4] + wredp[0*16 + (qb*2+1)*4 + qi4]) * (1.f/128.f);
                float msq = (wredp[1*16 + (qb*2)*4 + qi4] + wredp[1*16 + (qb*2+1)*4 + qi4]) * (1.f/128.f);
                float var = msq - mu*mu;
                float nv  = (hv[qi4]-mu) * __frsqrt_rn(var + 1e-5f) * g + b;
                res[qi4] = mask_s[sr*8 + qb*4+qi4] ? nv : qv[qi4];
            }
            float4 o; o.x=res[0]; o.y=res[1]; o.z=res[2]; o.w=res[3];
            *(float4*)(dout + (size_t)r*NQ + nsr + qb*4) = o;
        }
        __syncthreads();   // out2/desc region + wredp safe for next sub-round
    }
}

extern "C" void kernel_launch(void* const* d_in, const int* in_sizes, int n_in,
                              void* d_out, int out_size, void* d_ws, size_t ws_size,
                              hipStream_t stream){
    const float* scene  = (const float*)d_in[0];
    const float* f0     = (const float*)d_in[1];
    const float* f1     = (const float*)d_in[2];
    const float* f2     = (const float*)d_in[3];
    const float* depth  = (const float*)d_in[4];
    const float* K      = (const float*)d_in[5];
    const float* E      = (const float*)d_in[6];
    const float* vorig  = (const float*)d_in[7];
    const float* refpix = (const float*)d_in[8];
    const float* Wv     = (const float*)d_in[9];
    const float* bv     = (const float*)d_in[10];
    const float* Woff   = (const float*)d_in[11];
    const float* boff   = (const float*)d_in[12];
    const float* Wattw  = (const float*)d_in[13];
    const float* battw  = (const float*)d_in[14];
    const float* Wout   = (const float*)d_in[15];
    const float* bout   = (const float*)d_in[16];
    const float* lng    = (const float*)d_in[17];
    const float* lnb    = (const float*)d_in[18];

    char* ws = (char*)d_ws;
    // mask(131072) + value(2580480) + Wbf(114688)
    unsigned char*  mask   = (unsigned char*)(ws + 512);
    unsigned short* value  = (unsigned short*)(ws + 512 + 131072);
    unsigned short* Wbf    = (unsigned short*)(ws + 512 + 131072 + 2580480);
    unsigned short* WoutBf = Wbf + 40960;

    hipMemsetAsync(mask, 0, NQ, stream);

    int nW    = 57344/256;          // 224
    int nVal  = NVPIX/8;            // 1260
    int nMask = (NPIX+255)/256;     // 480
    prep_kernel<<<nW + nVal + nMask, 256, 0, stream>>>(
        nW, nVal, Woff, Wattw, Wout, Wbf,
        f0, f1, f2, Wv, bv, value,
        depth, K, E, vorig, mask);
    attn_fused<<<NQ/32, 256, 0, stream>>>(scene, refpix, Wbf, boff, battw, value,
                                          WoutBf, bout, lng, lnb, mask,
                                          (float*)d_out);
}